// Round 1
// baseline (174.273 us; speedup 1.0000x reference)
//
#include <hip/hip_runtime.h>

// Batched BFGS (quasi-Newton) solver, B=65536 independent problems, n=16.
// Layout: 16 lanes per batch (4 batches per wave64).
//   lane l owns: row l of h, column l of h (as hcol), row l of h_k,
//                element l of every n-vector (x, g, p, ...).
// Vector broadcasts: per-group 64B LDS slot (wave-synchronous, no barrier
// needed -- all 4 groups of a block's wave are in the SAME wave).
// Reductions: 4-stage __shfl_xor butterfly (width<16 masks stay in-group).

#define QN_N 16

__device__ __forceinline__ float redsum16(float v) {
    v += __shfl_xor(v, 1);
    v += __shfl_xor(v, 2);
    v += __shfl_xor(v, 4);
    v += __shfl_xor(v, 8);
    return v;
}

__device__ __forceinline__ float dot16(const float* a, const float* b) {
    float s0 = 0.f, s1 = 0.f, s2 = 0.f, s3 = 0.f;
#pragma unroll
    for (int k = 0; k < QN_N; k += 4) {
        s0 = fmaf(a[k + 0], b[k + 0], s0);
        s1 = fmaf(a[k + 1], b[k + 1], s1);
        s2 = fmaf(a[k + 2], b[k + 2], s2);
        s3 = fmaf(a[k + 3], b[k + 3], s3);
    }
    return (s0 + s1) + (s2 + s3);
}

// Broadcast: each lane contributes `val`; dst[0..15] receives the group's
// 16 values. Wave-synchronous LDS (write then uniform-address float4 reads).
#define BCAST(val, dst)                                   \
    do {                                                  \
        __builtin_amdgcn_wave_barrier();                  \
        slot[l] = (val);                                  \
        __builtin_amdgcn_wave_barrier();                  \
        float4 b0_ = ((const float4*)slot)[0];            \
        float4 b1_ = ((const float4*)slot)[1];            \
        float4 b2_ = ((const float4*)slot)[2];            \
        float4 b3_ = ((const float4*)slot)[3];            \
        (dst)[0] = b0_.x; (dst)[1] = b0_.y;               \
        (dst)[2] = b0_.z; (dst)[3] = b0_.w;               \
        (dst)[4] = b1_.x; (dst)[5] = b1_.y;               \
        (dst)[6] = b1_.z; (dst)[7] = b1_.w;               \
        (dst)[8] = b2_.x; (dst)[9] = b2_.y;               \
        (dst)[10] = b2_.z; (dst)[11] = b2_.w;             \
        (dst)[12] = b3_.x; (dst)[13] = b3_.y;             \
        (dst)[14] = b3_.z; (dst)[15] = b3_.w;             \
    } while (0)

__global__ __launch_bounds__(256, 4) void qn_kernel(
    const float* __restrict__ y, const float* __restrict__ h,
    const float* __restrict__ x0, const int* __restrict__ iter_p,
    float* __restrict__ out, int B)
{
    const int tid = blockIdx.x * blockDim.x + threadIdx.x;
    const int batch = tid >> 4;
    const int l = threadIdx.x & 15;
    if (batch >= B) return;
    const int iters = iter_p[0];

    __shared__ __align__(16) float bc[16][QN_N];   // one 64B slot per group
    float* slot = bc[threadIdx.x >> 4];

    const float* hb = h + (size_t)batch * (QN_N * QN_N);
    float hrow[QN_N], hcol[QN_N], hk[QN_N];
    {
        const float4* r4 = (const float4*)(hb + l * QN_N);
#pragma unroll
        for (int q = 0; q < 4; ++q) {
            float4 v = r4[q];
            hrow[4 * q + 0] = v.x; hrow[4 * q + 1] = v.y;
            hrow[4 * q + 2] = v.z; hrow[4 * q + 3] = v.w;
        }
    }
#pragma unroll
    for (int i = 0; i < QN_N; ++i) hcol[i] = hb[i * QN_N + l];   // L1 hits
#pragma unroll
    for (int i = 0; i < QN_N; ++i) hk[i] = (i == l) ? 1.0f : 0.0f;

    const float yl = y[batch * QN_N + l];
    float xl = x0[batch * QN_N + l];
    float alpha = 1.0f;          // persists across outer iterations (as in ref)

    float tmp[QN_N];

    // hx = (H x)_l
    BCAST(xl, tmp);
    float hx = dot16(hrow, tmp);
    // g = (H^T (Hx - y))_l
    BCAST(hx - yl, tmp);
    float g = dot16(hcol, tmp);

    for (int it = 0; it < iters; ++it) {
        // p = -(h_k @ g)
        BCAST(g, tmp);
        float p = -dot16(hk, tmp);
        float gtp = redsum16(g * p);
        // hp = (H p)_l  -> line-search trials become O(1)
        BCAST(p, tmp);
        float hp = dot16(hrow, tmp);
        // fx = 0.5*||y - Hx||
        float r0 = yl - hx;
        float fx = 0.5f * sqrtf(redsum16(r0 * r0));

        // --- backtracking Armijo line search (per-batch independent) ---
        float a = alpha;
        float hxa;
        for (;;) {
            hxa = hx + a * hp;
            float res = yl - hxa;
            float lhs = 0.5f * sqrtf(redsum16(res * res));
            float rhs = fx + 1e-4f * a * gtp;
            bool fail = lhs > rhs;        // group-uniform (lhs,rhs uniform)
            if (!__any(fail)) break;      // wave-wide any over 4 groups
            if (fail) a *= 0.5f;          // only violating groups shrink
        }
        alpha = a;

        // step
        float ap = a * p;
        float xn = xl + ap;
        float s = xn - xl;                 // match ref: x_new - x
        float hxn = hxa;                   // H x_new (from accepted trial)

        // g_new = H^T (H x_new - y)
        BCAST(hxn - yl, tmp);
        float gn = dot16(hcol, tmp);
        float yk = gn - g;

        // Hy = h_k @ yk   (h_k symmetric bit-exactly, so yk^T h_k = Hy^T)
        BCAST(yk, tmp);
        float hy = dot16(hk, tmp);

        float aux = redsum16(s * yk);      // s^T yk
        float yhy = redsum16(yk * hy);     // yk^T h_k yk
        float inv_aux = 1.0f / aux;
        float inv_aux2 = 1.0f / (aux * aux);
        float A1 = aux + yhy;

        float sv[QN_N], hyv[QN_N];
        BCAST(s, sv);
        BCAST(hy, hyv);
#pragma unroll
        for (int k = 0; k < QN_N; ++k) {
            float t1 = (A1 * (s * sv[k])) * inv_aux2;
            float t2 = (hy * sv[k] + s * hyv[k]) * inv_aux;
            hk[k] = (hk[k] + t1) - t2;
        }

        xl = xn;
        hx = hxn;
        g = gn;
    }

    out[batch * QN_N + l] = xl;
}

extern "C" void kernel_launch(void* const* d_in, const int* in_sizes, int n_in,
                              void* d_out, int out_size, void* d_ws, size_t ws_size,
                              hipStream_t stream) {
    const float* y  = (const float*)d_in[0];
    const float* h  = (const float*)d_in[1];
    const float* x0 = (const float*)d_in[2];
    const int* itp  = (const int*)d_in[3];
    float* out = (float*)d_out;

    const int B = in_sizes[0] / QN_N;      // 65536
    const int threads = B * QN_N;          // one 16-lane group per batch
    const int blocks = (threads + 255) / 256;
    qn_kernel<<<blocks, 256, 0, stream>>>(y, h, x0, itp, out, B);
}

// Round 2
// 168.990 us; speedup vs baseline: 1.0313x; 1.0313x over previous
//
#include <hip/hip_runtime.h>

// Batched BFGS (quasi-Newton), B=65536 independent problems, n=16.
// 16 lanes per batch, 4 batches per wave64.
//   lane l owns: row l of h, column l of h, row l of h_k (all as float2 pairs),
//                element l of every n-vector.
// Round-2 change vs round-1: packed-FP32 math (v_pk_fma_f32) for the dots and
// the rank-2 h_k update; paired (float2) butterfly reductions; fused s/hy
// broadcast; wider LDS slot stride (bank spread).

#define QN_N 16

typedef float f32x2 __attribute__((ext_vector_type(2)));

#define SLOT_STRIDE 40   // floats per group slot (160B): read banks disjoint

__device__ __forceinline__ float redsum16(float v) {
    v += __shfl_xor(v, 1);
    v += __shfl_xor(v, 2);
    v += __shfl_xor(v, 4);
    v += __shfl_xor(v, 8);
    return v;
}

// packed pair reduction; per-component add order identical to redsum16
__device__ __forceinline__ f32x2 redsum16p(f32x2 v) {
#pragma unroll
    for (int m = 1; m <= 8; m <<= 1) {
        f32x2 o;
        o.x = __shfl_xor(v.x, m);
        o.y = __shfl_xor(v.y, m);
        v = v + o;
    }
    return v;
}

// 16-dot over float2 pairs -> v_pk_fma_f32
__device__ __forceinline__ float dot16p(const f32x2* a, const f32x2* b) {
    f32x2 s0 = {0.f, 0.f}, s1 = {0.f, 0.f}, s2 = {0.f, 0.f}, s3 = {0.f, 0.f};
    s0 = __builtin_elementwise_fma(a[0], b[0], s0);
    s1 = __builtin_elementwise_fma(a[1], b[1], s1);
    s2 = __builtin_elementwise_fma(a[2], b[2], s2);
    s3 = __builtin_elementwise_fma(a[3], b[3], s3);
    s0 = __builtin_elementwise_fma(a[4], b[4], s0);
    s1 = __builtin_elementwise_fma(a[5], b[5], s1);
    s2 = __builtin_elementwise_fma(a[6], b[6], s2);
    s3 = __builtin_elementwise_fma(a[7], b[7], s3);
    f32x2 t = (s0 + s1) + (s2 + s3);
    return t.x + t.y;
}

// Broadcast one value per lane -> dst2[0..7] (8 float2 = the group's 16 vals).
// Wave-synchronous: all 4 groups of this block-wave are in the SAME wave.
#define BCASTP(val, dst2)                                  \
    do {                                                   \
        __builtin_amdgcn_wave_barrier();                   \
        slot[l] = (val);                                   \
        __builtin_amdgcn_wave_barrier();                   \
        _Pragma("unroll")                                  \
        for (int q_ = 0; q_ < 4; ++q_) {                   \
            float4 f_ = ((const float4*)slot)[q_];         \
            (dst2)[2 * q_]     = (f32x2){f_.x, f_.y};      \
            (dst2)[2 * q_ + 1] = (f32x2){f_.z, f_.w};      \
        }                                                  \
    } while (0)

// Fused broadcast of two values per lane (one ds_write2 + shared barriers).
#define BCAST2P(va, vb, dstA2, dstB2)                      \
    do {                                                   \
        __builtin_amdgcn_wave_barrier();                   \
        slot[l] = (va);                                    \
        slot[16 + l] = (vb);                               \
        __builtin_amdgcn_wave_barrier();                   \
        _Pragma("unroll")                                  \
        for (int q_ = 0; q_ < 4; ++q_) {                   \
            float4 fa_ = ((const float4*)slot)[q_];        \
            float4 fb_ = ((const float4*)(slot + 16))[q_]; \
            (dstA2)[2 * q_]     = (f32x2){fa_.x, fa_.y};   \
            (dstA2)[2 * q_ + 1] = (f32x2){fa_.z, fa_.w};   \
            (dstB2)[2 * q_]     = (f32x2){fb_.x, fb_.y};   \
            (dstB2)[2 * q_ + 1] = (f32x2){fb_.z, fb_.w};   \
        }                                                  \
    } while (0)

__global__ __launch_bounds__(256, 4) void qn_kernel(
    const float* __restrict__ y, const float* __restrict__ h,
    const float* __restrict__ x0, const int* __restrict__ iter_p,
    float* __restrict__ out, int B)
{
    const int tid = blockIdx.x * blockDim.x + threadIdx.x;
    const int batch = tid >> 4;
    const int l = threadIdx.x & 15;
    if (batch >= B) return;
    const int iters = iter_p[0];

    __shared__ __align__(16) float bc[16][SLOT_STRIDE];
    float* slot = bc[threadIdx.x >> 4];

    const float* hb = h + (size_t)batch * (QN_N * QN_N);
    f32x2 hrow2[8], hcol2[8], hk2[8];
    {
        const float4* r4 = (const float4*)(hb + l * QN_N);
#pragma unroll
        for (int q = 0; q < 4; ++q) {
            float4 v = r4[q];
            hrow2[2 * q]     = (f32x2){v.x, v.y};
            hrow2[2 * q + 1] = (f32x2){v.z, v.w};
        }
    }
#pragma unroll
    for (int i = 0; i < 8; ++i)        // L1 hits (rows already pulled by group)
        hcol2[i] = (f32x2){hb[(2 * i) * QN_N + l], hb[(2 * i + 1) * QN_N + l]};
#pragma unroll
    for (int i = 0; i < 8; ++i)
        hk2[i] = (f32x2){(2 * i == l) ? 1.0f : 0.0f, (2 * i + 1 == l) ? 1.0f : 0.0f};

    const float yl = y[batch * QN_N + l];
    float xl = x0[batch * QN_N + l];
    float alpha = 1.0f;          // persists across outer iterations (as in ref)

    f32x2 tmp2[8];

    // hx = (H x)_l
    BCASTP(xl, tmp2);
    float hx = dot16p(hrow2, tmp2);
    // g = (H^T (Hx - y))_l
    BCASTP(hx - yl, tmp2);
    float g = dot16p(hcol2, tmp2);

    for (int it = 0; it < iters; ++it) {
        // p = -(h_k @ g)
        BCASTP(g, tmp2);
        float p = -dot16p(hk2, tmp2);
        // hp = (H p)_l  -> line-search trials become O(1)
        BCASTP(p, tmp2);
        float hp = dot16p(hrow2, tmp2);

        // gtp = g^T p  and  ||r0||^2  via one packed butterfly
        float r0 = yl - hx;
        f32x2 pr = redsum16p((f32x2){g * p, r0 * r0});
        float gtp = pr.x;
        float fx = 0.5f * sqrtf(pr.y);

        // --- backtracking Armijo line search (per-batch independent) ---
        float a = alpha;
        float hxa;
        for (;;) {
            hxa = hx + a * hp;
            float res = yl - hxa;
            float lhs = 0.5f * sqrtf(redsum16(res * res));
            float rhs = fx + 1e-4f * a * gtp;
            bool fail = lhs > rhs;        // group-uniform
            if (!__any(fail)) break;      // wave-wide any over 4 groups
            if (fail) a *= 0.5f;          // only violating groups shrink
        }
        alpha = a;

        // step
        float xn = xl + a * p;
        float s = xn - xl;                 // match ref: x_new - x (exact)
        float hxn = hxa;                   // H x_new (accepted trial)

        // g_new = H^T (H x_new - y)
        BCASTP(hxn - yl, tmp2);
        float gn = dot16p(hcol2, tmp2);
        float yk = gn - g;

        // Hy = h_k @ yk  (h_k bit-exactly symmetric => yk^T h_k = Hy^T)
        BCASTP(yk, tmp2);
        float hy = dot16p(hk2, tmp2);

        // aux = s^T yk, yhy = yk^T h_k yk via one packed butterfly
        f32x2 ay = redsum16p((f32x2){s * yk, yk * hy});
        float aux = ay.x, yhy = ay.y;
        float inv_aux = 1.0f / aux;
        float inv_aux2 = 1.0f / (aux * aux);
        float A1 = aux + yhy;

        // rank-2 h_k update, packed:
        //   hk += (A1*inv2*s)*sv - ((hy*inv)*sv + (s*inv)*hyv)
        f32x2 sv2[8], hyv2[8];
        BCAST2P(s, hy, sv2, hyv2);
        float c1s = (A1 * inv_aux2) * s;
        float c2s = s * inv_aux;
        float c3s = hy * inv_aux;
        f32x2 c1p = {c1s, c1s}, c2p = {c2s, c2s}, c3p = {c3s, c3s};
#pragma unroll
        for (int j = 0; j < 8; ++j) {
            f32x2 u = __builtin_elementwise_fma(c1p, sv2[j], hk2[j]);
            f32x2 t = c3p * sv2[j];
            t = __builtin_elementwise_fma(c2p, hyv2[j], t);
            hk2[j] = u - t;
        }

        xl = xn;
        hx = hxn;
        g = gn;
    }

    out[batch * QN_N + l] = xl;
}

extern "C" void kernel_launch(void* const* d_in, const int* in_sizes, int n_in,
                              void* d_out, int out_size, void* d_ws, size_t ws_size,
                              hipStream_t stream) {
    const float* y  = (const float*)d_in[0];
    const float* h  = (const float*)d_in[1];
    const float* x0 = (const float*)d_in[2];
    const int* itp  = (const int*)d_in[3];
    float* out = (float*)d_out;

    const int B = in_sizes[0] / QN_N;      // 65536
    const int threads = B * QN_N;
    const int blocks = (threads + 255) / 256;
    qn_kernel<<<blocks, 256, 0, stream>>>(y, h, x0, itp, out, B);
}

// Round 3
// 159.952 us; speedup vs baseline: 1.0895x; 1.0565x over previous
//
#include <hip/hip_runtime.h>

// Batched BFGS (quasi-Newton), B=65536 independent problems, n=16.
// 16 lanes per batch, 4 batches per wave64.
//   lane l owns: row l of h, column l of h, row l of h_k (as float2 pairs),
//                element l of every n-vector.
// Round-3 changes vs round-2:
//  * All 16-lane reductions via DPP v_add_f32 chains (quad_perm xor1/xor2 +
//    row_mirror + row_half_mirror) -- pure VALU, ~5x lower latency than the
//    ds_swizzle chains __shfl_xor generates. Mirror pattern => bitwise-equal
//    result in all 16 lanes (group-uniform line-search decisions preserved).
//  * One LDS broadcast fewer per iter: gn~ is kept in registers as next
//    iteration's g~; yk~ = gn~ - g~ via packed subs.
//  * LDS layout reverted to the round-1 empirically conflict-free pattern:
//    two [16][16] float arrays (64B slot stride). Round-2's stride-40 counted
//    2.03M bank conflicts; stride-16 counted 0.

#define QN_N 16

typedef float f32x2 __attribute__((ext_vector_type(2)));

union F4 {
    float4 v4;
    f32x2  v2[2];
};

// ---- DPP 16-lane all-reduce (sum), bitwise-uniform across the 16 lanes ----
template <int CTRL>
__device__ __forceinline__ float dpp_add(float v) {
    int s = __builtin_bit_cast(int, v);
    int t = __builtin_amdgcn_update_dpp(s, s, CTRL, 0xF, 0xF, false);
    return v + __builtin_bit_cast(float, t);
}

__device__ __forceinline__ float redsum16(float v) {
    v = dpp_add<0xB1>(v);    // quad_perm [1,0,3,2]  : + lane^1
    v = dpp_add<0x4E>(v);    // quad_perm [2,3,0,1]  : + lane^2  -> quad sums
    v = dpp_add<0x140>(v);   // row_mirror           : quad q <-> 3-q
    v = dpp_add<0x141>(v);   // row_half_mirror      : quad q <-> q^1
    return v;
}

__device__ __forceinline__ f32x2 redsum16p(f32x2 v) {
    // two independent scalar DPP chains (interleave in the pipeline)
    f32x2 r;
    r.x = redsum16(v.x);
    r.y = redsum16(v.y);
    return r;
}

// 16-dot over float2 pairs -> v_pk_fma_f32
__device__ __forceinline__ float dot16p(const f32x2* a, const f32x2* b) {
    f32x2 s0 = {0.f, 0.f}, s1 = {0.f, 0.f}, s2 = {0.f, 0.f}, s3 = {0.f, 0.f};
    s0 = __builtin_elementwise_fma(a[0], b[0], s0);
    s1 = __builtin_elementwise_fma(a[1], b[1], s1);
    s2 = __builtin_elementwise_fma(a[2], b[2], s2);
    s3 = __builtin_elementwise_fma(a[3], b[3], s3);
    s0 = __builtin_elementwise_fma(a[4], b[4], s0);
    s1 = __builtin_elementwise_fma(a[5], b[5], s1);
    s2 = __builtin_elementwise_fma(a[6], b[6], s2);
    s3 = __builtin_elementwise_fma(a[7], b[7], s3);
    f32x2 t = (s0 + s1) + (s2 + s3);
    return t.x + t.y;
}

// Broadcast: each lane contributes val; dst2[0..7] receives the group's 16
// values. Wave-synchronous (all 4 groups of this slot-array are in one wave).
__device__ __forceinline__ void bcast16(float* slot, int l, float val,
                                        f32x2* dst2) {
    __builtin_amdgcn_wave_barrier();
    slot[l] = val;
    __builtin_amdgcn_wave_barrier();
#pragma unroll
    for (int q = 0; q < 4; ++q) {
        F4 f;
        f.v4 = ((const float4*)slot)[q];
        dst2[2 * q]     = f.v2[0];
        dst2[2 * q + 1] = f.v2[1];
    }
}

// Fused double broadcast through two independent [16][16] arrays.
__device__ __forceinline__ void bcast16x2(float* slotA, float* slotB, int l,
                                          float va, float vb,
                                          f32x2* dstA2, f32x2* dstB2) {
    __builtin_amdgcn_wave_barrier();
    slotA[l] = va;
    slotB[l] = vb;
    __builtin_amdgcn_wave_barrier();
#pragma unroll
    for (int q = 0; q < 4; ++q) {
        F4 fa, fb;
        fa.v4 = ((const float4*)slotA)[q];
        fb.v4 = ((const float4*)slotB)[q];
        dstA2[2 * q]     = fa.v2[0];
        dstA2[2 * q + 1] = fa.v2[1];
        dstB2[2 * q]     = fb.v2[0];
        dstB2[2 * q + 1] = fb.v2[1];
    }
}

__global__ __launch_bounds__(256, 4) void qn_kernel(
    const float* __restrict__ y, const float* __restrict__ h,
    const float* __restrict__ x0, const int* __restrict__ iter_p,
    float* __restrict__ out, int B)
{
    const int tid = blockIdx.x * blockDim.x + threadIdx.x;
    const int batch = tid >> 4;
    const int l = threadIdx.x & 15;
    if (batch >= B) return;
    const int iters = iter_p[0];

    __shared__ __align__(16) float bcA[16][QN_N];  // round-1 layout: 0 conflicts
    __shared__ __align__(16) float bcB[16][QN_N];
    float* slotA = bcA[threadIdx.x >> 4];
    float* slotB = bcB[threadIdx.x >> 4];

    const float* hb = h + (size_t)batch * (QN_N * QN_N);
    f32x2 hrow2[8], hcol2[8], hk2[8];
    {
        const float4* r4 = (const float4*)(hb + l * QN_N);
#pragma unroll
        for (int q = 0; q < 4; ++q) {
            F4 f;
            f.v4 = r4[q];
            hrow2[2 * q]     = f.v2[0];
            hrow2[2 * q + 1] = f.v2[1];
        }
    }
#pragma unroll
    for (int i = 0; i < 8; ++i)        // L1 hits (rows already pulled by group)
        hcol2[i] = (f32x2){hb[(2 * i) * QN_N + l], hb[(2 * i + 1) * QN_N + l]};
#pragma unroll
    for (int i = 0; i < 8; ++i)
        hk2[i] = (f32x2){(2 * i == l) ? 1.0f : 0.0f,
                         (2 * i + 1 == l) ? 1.0f : 0.0f};

    const float yl = y[batch * QN_N + l];
    float xl = x0[batch * QN_N + l];
    float alpha = 1.0f;          // persists across outer iterations (as in ref)

    f32x2 gv2[8], tA[8], tB[8], sv2[8];

    // hx = (H x)_l
    bcast16(slotA, l, xl, tA);
    float hx = dot16p(hrow2, tA);
    // g = (H^T (Hx - y))_l
    bcast16(slotA, l, hx - yl, tA);
    float g = dot16p(hcol2, tA);
    // g~ for the first iteration
    bcast16(slotA, l, g, gv2);

    for (int it = 0; it < iters; ++it) {
        // p = -(h_k @ g)   (g~ already in registers)
        float p = -dot16p(hk2, gv2);
        bcast16(slotA, l, p, tA);                  // trip 1: p~
        float hp = dot16p(hrow2, tA);              // (H p)_l

        // gtp = g^T p  and  ||r0||^2
        float r0 = yl - hx;
        f32x2 pr = redsum16p((f32x2){g * p, r0 * r0});
        float gtp = pr.x;
        float fx = 0.5f * sqrtf(pr.y);

        // --- backtracking Armijo line search (per-batch independent) ---
        float a = alpha;
        float hxa;
        for (;;) {
            hxa = hx + a * hp;
            float res = yl - hxa;
            float lhs = 0.5f * sqrtf(redsum16(res * res));
            float rhs = fx + 1e-4f * a * gtp;
            bool fail = lhs > rhs;        // group-uniform (DPP sum is uniform)
            if (!__any(fail)) break;      // wave-wide any over 4 groups
            if (fail) a *= 0.5f;          // only violating groups shrink
        }
        alpha = a;

        // step
        float xn = xl + a * p;
        float s = xn - xl;                 // match ref: x_new - x
        float hxn = hxa;                   // H x_new (accepted trial)
        float r = hxn - yl;

        // trip 2: r~ and s~ together
        bcast16x2(slotA, slotB, l, r, s, tA, sv2);
        float gn = dot16p(hcol2, tA);      // g_new = H^T (H x_new - y)
        float yk = gn - g;

        // trip 3: gn~ (becomes next iteration's g~)
        bcast16(slotA, l, gn, tB);
#pragma unroll
        for (int j = 0; j < 8; ++j)        // yk~ = gn~ - g~ (packed subs)
            tA[j] = tB[j] - gv2[j];
        float hy = dot16p(hk2, tA);        // Hy = h_k @ yk (h_k symmetric)
#pragma unroll
        for (int j = 0; j < 8; ++j)        // g~ <- gn~
            gv2[j] = tB[j];

        // aux = s^T yk, yhy = yk^T h_k yk
        f32x2 ay = redsum16p((f32x2){s * yk, yk * hy});
        float aux = ay.x, yhy = ay.y;
        float inv_aux = 1.0f / aux;
        float inv_aux2 = 1.0f / (aux * aux);
        float A1 = aux + yhy;

        // trip 4: hy~
        bcast16(slotA, l, hy, tB);

        // rank-2 h_k update, packed:
        //   hk += (A1*inv2*s)*sv - ((hy*inv)*sv + (s*inv)*hyv)
        float c1s = (A1 * inv_aux2) * s;
        float c2s = s * inv_aux;
        float c3s = hy * inv_aux;
        f32x2 c1p = {c1s, c1s}, c2p = {c2s, c2s}, c3p = {c3s, c3s};
#pragma unroll
        for (int j = 0; j < 8; ++j) {
            f32x2 u = __builtin_elementwise_fma(c1p, sv2[j], hk2[j]);
            f32x2 t = c3p * sv2[j];
            t = __builtin_elementwise_fma(c2p, tB[j], t);
            hk2[j] = u - t;
        }

        xl = xn;
        hx = hxn;
        g = gn;
    }

    out[batch * QN_N + l] = xl;
}

extern "C" void kernel_launch(void* const* d_in, const int* in_sizes, int n_in,
                              void* d_out, int out_size, void* d_ws, size_t ws_size,
                              hipStream_t stream) {
    const float* y  = (const float*)d_in[0];
    const float* h  = (const float*)d_in[1];
    const float* x0 = (const float*)d_in[2];
    const int* itp  = (const int*)d_in[3];
    float* out = (float*)d_out;

    const int B = in_sizes[0] / QN_N;      // 65536
    const int threads = B * QN_N;
    const int blocks = (threads + 255) / 256;
    qn_kernel<<<blocks, 256, 0, stream>>>(y, h, x0, itp, out, B);
}

// Round 6
// 151.630 us; speedup vs baseline: 1.1493x; 1.0549x over previous
//
#include <hip/hip_runtime.h>

// Batched BFGS (quasi-Newton), B=65536 independent problems, n=16.
// 16 lanes per batch, 4 batches per wave64.
//   lane l owns: row l of h, column l of h, row l of h_k (as float2 pairs),
//                element l of every n-vector.
// Round-6 = round-3 (proven-good on this harness) + closed-form Armijo:
//  * Closed-form Armijo trials: lhs(a)^2 = A - 2aB + a^2C with A,B,C reduced
//    once per outer iteration; per-trial = 3 fma + mul + 2 cmp, no DPP/sqrt,
//    no LDS. fail <=> (t<0) || (q > t^2), t = sqrt(A)+2c*a*gtp.
//  * Single exact division (1/aux), inv_aux2 = inv_aux^2.
//  * NO inline asm / novel builtins (rounds 4-5 died in harness with those;
//    this round uses only primitives that ran in round 3).

#define QN_N 16

typedef float f32x2 __attribute__((ext_vector_type(2)));

union F4 {
    float4 v4;
    f32x2  v2[2];
};

// ---- DPP 16-lane all-reduce (sum), bitwise-uniform across the 16 lanes ----
template <int CTRL>
__device__ __forceinline__ float dpp_add(float v) {
    int s = __builtin_bit_cast(int, v);
    int t = __builtin_amdgcn_update_dpp(s, s, CTRL, 0xF, 0xF, false);
    return v + __builtin_bit_cast(float, t);
}

__device__ __forceinline__ float redsum16(float v) {
    v = dpp_add<0xB1>(v);    // quad_perm [1,0,3,2]  : + lane^1
    v = dpp_add<0x4E>(v);    // quad_perm [2,3,0,1]  : + lane^2  -> quad sums
    v = dpp_add<0x140>(v);   // row_mirror           : quad q <-> 3-q
    v = dpp_add<0x141>(v);   // row_half_mirror      : quad q <-> q^1
    return v;
}

// 16-dot over float2 pairs -> v_pk_fma_f32
__device__ __forceinline__ float dot16p(const f32x2* a, const f32x2* b) {
    f32x2 s0 = {0.f, 0.f}, s1 = {0.f, 0.f}, s2 = {0.f, 0.f}, s3 = {0.f, 0.f};
    s0 = __builtin_elementwise_fma(a[0], b[0], s0);
    s1 = __builtin_elementwise_fma(a[1], b[1], s1);
    s2 = __builtin_elementwise_fma(a[2], b[2], s2);
    s3 = __builtin_elementwise_fma(a[3], b[3], s3);
    s0 = __builtin_elementwise_fma(a[4], b[4], s0);
    s1 = __builtin_elementwise_fma(a[5], b[5], s1);
    s2 = __builtin_elementwise_fma(a[6], b[6], s2);
    s3 = __builtin_elementwise_fma(a[7], b[7], s3);
    f32x2 t = (s0 + s1) + (s2 + s3);
    return t.x + t.y;
}

// Broadcast: each lane contributes val; dst2[0..7] receives the group's 16
// values. Wave-synchronous (all 4 groups of this slot-array are in one wave).
__device__ __forceinline__ void bcast16(float* slot, int l, float val,
                                        f32x2* dst2) {
    __builtin_amdgcn_wave_barrier();
    slot[l] = val;
    __builtin_amdgcn_wave_barrier();
#pragma unroll
    for (int q = 0; q < 4; ++q) {
        F4 f;
        f.v4 = ((const float4*)slot)[q];
        dst2[2 * q]     = f.v2[0];
        dst2[2 * q + 1] = f.v2[1];
    }
}

// Fused double broadcast through two independent [16][16] arrays.
__device__ __forceinline__ void bcast16x2(float* slotA, float* slotB, int l,
                                          float va, float vb,
                                          f32x2* dstA2, f32x2* dstB2) {
    __builtin_amdgcn_wave_barrier();
    slotA[l] = va;
    slotB[l] = vb;
    __builtin_amdgcn_wave_barrier();
#pragma unroll
    for (int q = 0; q < 4; ++q) {
        F4 fa, fb;
        fa.v4 = ((const float4*)slotA)[q];
        fb.v4 = ((const float4*)slotB)[q];
        dstA2[2 * q]     = fa.v2[0];
        dstA2[2 * q + 1] = fa.v2[1];
        dstB2[2 * q]     = fb.v2[0];
        dstB2[2 * q + 1] = fb.v2[1];
    }
}

__global__ __launch_bounds__(256, 4) void qn_kernel(
    const float* __restrict__ y, const float* __restrict__ h,
    const float* __restrict__ x0, const int* __restrict__ iter_p,
    float* __restrict__ out, int B)
{
    const int tid = blockIdx.x * blockDim.x + threadIdx.x;
    const int batch = tid >> 4;
    const int l = threadIdx.x & 15;
    if (batch >= B) return;
    const int iters = iter_p[0];

    __shared__ __align__(16) float bcA[16][QN_N];  // 0 bank conflicts (r1/r3)
    __shared__ __align__(16) float bcB[16][QN_N];
    float* slotA = bcA[threadIdx.x >> 4];
    float* slotB = bcB[threadIdx.x >> 4];

    const float* hb = h + (size_t)batch * (QN_N * QN_N);
    f32x2 hrow2[8], hcol2[8], hk2[8];
    {
        const float4* r4 = (const float4*)(hb + l * QN_N);
#pragma unroll
        for (int q = 0; q < 4; ++q) {
            F4 f;
            f.v4 = r4[q];
            hrow2[2 * q]     = f.v2[0];
            hrow2[2 * q + 1] = f.v2[1];
        }
    }
#pragma unroll
    for (int i = 0; i < 8; ++i)        // L1 hits (rows already pulled by group)
        hcol2[i] = (f32x2){hb[(2 * i) * QN_N + l], hb[(2 * i + 1) * QN_N + l]};
#pragma unroll
    for (int i = 0; i < 8; ++i)
        hk2[i] = (f32x2){(2 * i == l) ? 1.0f : 0.0f,
                         (2 * i + 1 == l) ? 1.0f : 0.0f};

    const float yl = y[batch * QN_N + l];
    float xl = x0[batch * QN_N + l];
    float alpha = 1.0f;          // persists across outer iterations (as in ref)

    f32x2 gv2[8], tA[8], tB[8], sv2[8];

    // hx = (H x)_l
    bcast16(slotA, l, xl, tA);
    float hx = dot16p(hrow2, tA);
    // g = (H^T (Hx - y))_l
    bcast16(slotA, l, hx - yl, tA);
    float g = dot16p(hcol2, tA);
    // g~ for the first iteration
    bcast16(slotA, l, g, gv2);

    for (int it = 0; it < iters; ++it) {
        // p = -(h_k @ g)   (g~ already in registers)
        float p = -dot16p(hk2, gv2);
        bcast16(slotA, l, p, tA);                  // trip 1: p~
        float hp = dot16p(hrow2, tA);              // (H p)_l

        // Four reductions (independent DPP chains, interleave in pipeline):
        //   gtp = g.p, A = |r0|^2, Bv = r0.hp, Cv = |hp|^2
        float r0 = yl - hx;
        float gtp = redsum16(g * p);
        float A   = redsum16(r0 * r0);
        float Bv  = redsum16(r0 * hp);
        float Cv  = redsum16(hp * hp);

        float sA  = sqrtf(A);              // 2*fx
        float cg2 = 2.0f * 1e-4f * gtp;
        float m2B = -2.0f * Bv;

        // --- backtracking Armijo, closed-form trials ---
        // lhs(a) = 0.5*sqrt(A - 2aB + a^2 C); fail <=> lhs > fx + c*a*gtp
        //      <=> (t < 0) || (q > t^2),  t = sA + 2c*a*gtp, q = A - 2aB + a^2C
        float a = alpha;
        for (;;) {
            float t = fmaf(cg2, a, sA);
            float q = fmaf(a, fmaf(a, Cv, m2B), A);
            bool fail = (t < 0.0f) | (q > t * t);
            if (!__any(fail)) break;       // wave-wide any over 4 groups
            if (fail) a *= 0.5f;           // only violating groups shrink
        }
        alpha = a;

        // step
        float xn  = xl + a * p;
        float s   = xn - xl;               // match ref: x_new - x
        float hxn = fmaf(a, hp, hx);       // H x_new (accepted-trial value)
        float r   = hxn - yl;

        // trip 2: r~ and s~ together
        bcast16x2(slotA, slotB, l, r, s, tA, sv2);
        float gn = dot16p(hcol2, tA);      // g_new = H^T (H x_new - y)

        // trip 3: gn~ (becomes next iteration's g~)
        bcast16(slotA, l, gn, tB);
#pragma unroll
        for (int j = 0; j < 8; ++j)        // yk~ = gn~ - g~ (packed subs)
            tA[j] = tB[j] - gv2[j];
        float yk = gn - g;
        float hy = dot16p(hk2, tA);        // Hy = h_k @ yk (h_k symmetric)
#pragma unroll
        for (int j = 0; j < 8; ++j)        // g~ <- gn~
            gv2[j] = tB[j];

        // aux = s^T yk, yhy = yk^T h_k yk
        float aux = redsum16(s * yk);
        float yhy = redsum16(yk * hy);
        float inv_aux  = 1.0f / aux;       // one exact div (was two)
        float inv_aux2 = inv_aux * inv_aux;
        float A1 = aux + yhy;

        // trip 4: hy~
        bcast16(slotA, l, hy, tB);

        // rank-2 h_k update, packed:
        //   hk += (A1*inv2*s)*sv - ((hy*inv)*sv + (s*inv)*hyv)
        float c1s = (A1 * inv_aux2) * s;
        float c2s = s * inv_aux;
        float c3s = hy * inv_aux;
        f32x2 c1p = {c1s, c1s}, c2p = {c2s, c2s}, c3p = {c3s, c3s};
#pragma unroll
        for (int j = 0; j < 8; ++j) {
            f32x2 u = __builtin_elementwise_fma(c1p, sv2[j], hk2[j]);
            f32x2 t = c3p * sv2[j];
            t = __builtin_elementwise_fma(c2p, tB[j], t);
            hk2[j] = u - t;
        }

        xl = xn;
        hx = hxn;
        g = gn;
    }

    out[batch * QN_N + l] = xl;
}

extern "C" void kernel_launch(void* const* d_in, const int* in_sizes, int n_in,
                              void* d_out, int out_size, void* d_ws, size_t ws_size,
                              hipStream_t stream) {
    const float* y  = (const float*)d_in[0];
    const float* h  = (const float*)d_in[1];
    const float* x0 = (const float*)d_in[2];
    const int* itp  = (const int*)d_in[3];
    float* out = (float*)d_out;

    const int B = in_sizes[0] / QN_N;      // 65536
    const int threads = B * QN_N;
    const int blocks = (threads + 255) / 256;
    qn_kernel<<<blocks, 256, 0, stream>>>(y, h, x0, itp, out, B);
}